// Round 15
// baseline (222.933 us; speedup 1.0000x reference)
//
#include <hip/hip_runtime.h>
#include <hip/hip_bf16.h>
#include <math.h>

#define B_SZ 16
#define L_SEQ 128
#define D_M 32
#define HW 65536           // 256*256 elements per (b,c) row

typedef float vfloat4 __attribute__((ext_vector_type(4)));

// Device-global scratch (all counters self-reset each run)
__device__ float g_part[B_SZ * L_SEQ];            // per-row maxima (1 block per row)
__device__ float g_y[2][B_SZ * D_M * L_SEQ];      // per-dir y, [b][d][l], fwd orientation
__device__ int   g_cnt[B_SZ];                     // streaming arrival counters
__device__ int   g_done[B_SZ];                    // tail-pair arrival counters

__device__ __forceinline__ float silu_acc(float x) {
    return x / (1.f + __expf(-x));
}
__device__ __forceinline__ float softplusf(float x) {
    return (x > 20.f) ? x : log1pf(__expf(x));
}

// ---------------- single fused kernel: stream + per-batch overlapped tail ----------------
// LDS word map (15136 words = 60.5 KB):
//  [0,4352)      sx  [32][136] pad4 / sdl overlay [128][33] / sv overlay [128][33] (final)
//  [4352,8576)   su  [32][132]
//  [8576,12800)  sy  [32][132]
//  [12800,13056) sdt [128][2]
//  [13056,14080) sB  [128][8]
//  [14080,15104) sC  [128][8]
//  [15104,15136) smm [32]
__global__ __launch_bounds__(512) void fused(
    const float* __restrict__ x,
    const float* __restrict__ w1,  const float* __restrict__ b1,
    const float* __restrict__ lng, const float* __restrict__ lnb,
    const float* __restrict__ Win,
    const float* __restrict__ cw_f, const float* __restrict__ cb_f,
    const float* __restrict__ xp_f, const float* __restrict__ dtw_f,
    const float* __restrict__ dtb_f, const float* __restrict__ Al_f,
    const float* __restrict__ Dp_f,
    const float* __restrict__ cw_b, const float* __restrict__ cb_b,
    const float* __restrict__ xp_b, const float* __restrict__ dtw_b,
    const float* __restrict__ dtb_b, const float* __restrict__ Al_b,
    const float* __restrict__ Dp_b,
    const float* __restrict__ ng,  const float* __restrict__ nb,
    const float* __restrict__ Wout, const float* __restrict__ w2,
    const float* __restrict__ b2,  float* __restrict__ out) {
    const int row = blockIdx.x;          // 0..2047 = (b<<7) | c
    const int b   = row >> 7;
    const int tid = threadIdx.x;

    __shared__ __align__(16) float S[15136];
    __shared__ float s_m[8];
    __shared__ int s_flag;

    // ---- Stage A: stream this row (256 KB), NT loads, 4 accumulators ----
    {
        const vfloat4* __restrict__ p =
            reinterpret_cast<const vfloat4*>(x) + (size_t)row * 16384;
        float m0 = -INFINITY, m1 = -INFINITY, m2 = -INFINITY, m3 = -INFINITY;
#pragma unroll
        for (int i = 0; i < 16384; i += 2048) {
            vfloat4 v0 = __builtin_nontemporal_load(p + i + tid);
            vfloat4 v1 = __builtin_nontemporal_load(p + i + tid + 512);
            vfloat4 v2 = __builtin_nontemporal_load(p + i + tid + 1024);
            vfloat4 v3 = __builtin_nontemporal_load(p + i + tid + 1536);
            m0 = fmaxf(m0, fmaxf(fmaxf(v0.x, v0.y), fmaxf(v0.z, v0.w)));
            m1 = fmaxf(m1, fmaxf(fmaxf(v1.x, v1.y), fmaxf(v1.z, v1.w)));
            m2 = fmaxf(m2, fmaxf(fmaxf(v2.x, v2.y), fmaxf(v2.z, v2.w)));
            m3 = fmaxf(m3, fmaxf(fmaxf(v3.x, v3.y), fmaxf(v3.z, v3.w)));
        }
        float m = fmaxf(fmaxf(m0, m1), fmaxf(m2, m3));
#pragma unroll
        for (int off = 32; off >= 1; off >>= 1)
            m = fmaxf(m, __shfl_xor(m, off));
        if ((tid & 63) == 0) s_m[tid >> 6] = m;
        __syncthreads();
        if (tid == 0) {
            float mm = s_m[0];
#pragma unroll
            for (int w = 1; w < 8; w++) mm = fmaxf(mm, s_m[w]);
            g_part[row] = mm;
            __threadfence();
            atomicAdd(&g_cnt[b], 1);
        }
    }
    if ((row & 127) >= 2) return;        // only 2 tail blocks per batch

    // ---- Tail block: wait for this batch's 128 rows ----
    const int dir = row & 1;
    if (tid == 0) {
        while (atomicAdd(&g_cnt[b], 0) < 128) __builtin_amdgcn_s_sleep(8);
        __threadfence();
    }
    __syncthreads();

    const float* cw  = dir ? cw_b  : cw_f;
    const float* cb  = dir ? cb_b  : cb_f;
    const float* xp  = dir ? xp_b  : xp_f;
    const float* dtw = dir ? dtw_b : dtw_f;
    const float* dtb = dir ? dtb_b : dtb_f;
    const float* Al  = dir ? Al_b  : Al_f;
    const float* Dp  = dir ? Dp_b  : Dp_f;

    float* sx  = S;            // [32][136], data at +4
    float* sdl = S;            // [128][33] overlay
    float* su  = S + 4352;     // [32][132]
    float* sy  = S + 8576;     // [32][132]
    float* sdt = S + 12800;    // [128][2]
    float* sB  = S + 13056;    // [128][8]
    float* sC  = S + 14080;    // [128][8]
    float* smm = S + 15104;    // [32]

    const int l = tid & 127;
    const int q = tid >> 7;    // 0..3 (wave-uniform: q = wave>>1)
    const int qq = __builtin_amdgcn_readfirstlane(q);

    // Phase 1: zero conv front-pad; m = Wout^T @ w2; h in registers
    if (tid < 128) sx[(tid >> 2) * 136 + (tid & 3)] = 0.f;
    if (tid >= 128 && tid < 160) {
        const int d = tid - 128;
        float mm = 0.f;
#pragma unroll
        for (int o = 0; o < D_M; o++) mm += w2[o] * Wout[o * 32 + d];
        smm[d] = mm;
    }
    float h[D_M];
    {
        const float s = g_part[b * L_SEQ + l];
        float mean = 0.f;
#pragma unroll
        for (int d = 0; d < D_M; d++) { h[d] = s * w1[d] + b1[d]; mean += h[d]; }
        mean *= (1.f / D_M);
        float var = 0.f;
#pragma unroll
        for (int d = 0; d < D_M; d++) { float t = h[d] - mean; var += t * t; }
        var *= (1.f / D_M);
        const float rs = rsqrtf(var + 1e-5f);
#pragma unroll
        for (int d = 0; d < D_M; d++) h[d] = (h[d] - mean) * rs * lng[d] + lnb[d];
    }

    // Phase 2: x-half GEMV, 8 rows/thread, stored pre-flipped
    {
        const int lw = dir ? (127 - l) : l;
#pragma unroll
        for (int k = 0; k < 8; k++) {
            const int e = qq * 8 + k;
            float acc = 0.f;
#pragma unroll
            for (int d = 0; d < D_M; d++) acc += h[d] * Win[e * 32 + d];
            sx[e * 136 + 4 + lw] = acc;
        }
    }

    // z pre-compute: zs[k] = silu(z[qq*8+k])
    float zs[8];
#pragma unroll
    for (int k = 0; k < 8; k++) {
        const int d = qq * 8 + k;
        float z = 0.f;
#pragma unroll
        for (int kk = 0; kk < D_M; kk++) z += h[kk] * Win[(32 + d) * 32 + kk];
        zs[k] = silu_acc(z);
    }
    __syncthreads();

    // Phase 3: causal conv(4) + SiLU; thread = (d, 8-l block)
    {
        const int d  = tid >> 4;          // 0..31
        const int l0 = (tid & 15) * 8;    // 0,8,...,120
        const vfloat4* px = reinterpret_cast<const vfloat4*>(sx + d * 136 + l0);
        vfloat4 a0 = px[0], a1 = px[1], a2 = px[2];
        float xv[12] = {a0.x,a0.y,a0.z,a0.w, a1.x,a1.y,a1.z,a1.w, a2.x,a2.y,a2.z,a2.w};
        const float c0 = cw[d*4+0], c1 = cw[d*4+1], c2 = cw[d*4+2], c3 = cw[d*4+3];
        const float cbd = cb[d];
        float uo[8];
#pragma unroll
        for (int j = 0; j < 8; j++) {
            float acc = cbd + c0*xv[j+1] + c1*xv[j+2] + c2*xv[j+3] + c3*xv[j+4];
            uo[j] = silu_acc(acc);
        }
        vfloat4 u0 = {uo[0],uo[1],uo[2],uo[3]}, u1 = {uo[4],uo[5],uo[6],uo[7]};
        vfloat4* pu = reinterpret_cast<vfloat4*>(su + d * 132 + l0);
        pu[0] = u0; pu[1] = u1;
    }
    __syncthreads();

    // Phase 4: x_dbl = u^T @ xp^T; rows r = qq + rep*4 (18 rows total)
    {
        float ul[D_M];
#pragma unroll
        for (int d = 0; d < D_M; d++) ul[d] = su[d * 132 + l];
#pragma unroll
        for (int rep = 0; rep < 5; rep++) {
            const int r = qq + rep * 4;
            if (rep == 4 && qq >= 2) break;
            float acc = 0.f;
#pragma unroll
            for (int d = 0; d < D_M; d++) acc += ul[d] * xp[r * 32 + d];
            if (r < 2)       sdt[l * 2 + r] = acc;
            else if (r < 10) sB[l * 8 + (r - 2)] = acc;
            else             sC[l * 8 + (r - 10)] = acc;
        }
    }
    __syncthreads();

    // Phase 5: delta = softplus(dt @ dtw^T + dtb), overlays sx; 8 d's/thread
    {
        const float dt0 = sdt[l * 2 + 0], dt1 = sdt[l * 2 + 1];
        const int d0 = qq * 8;
#pragma unroll
        for (int j = 0; j < 8; j++) {
            const int d = d0 + j;
            const float t = dt0 * dtw[d * 2 + 0] + dt1 * dtw[d * 2 + 1] + dtb[d];
            sdl[l * 33 + d] = softplusf(t);
        }
    }
    __syncthreads();

    // Phase 6: chunked scan, thread = (d, c): 256 threads, 8 n-states in regs
    if (tid < 256) {
        const int d = tid >> 3;
        const int c = tid & 7;
        float An[8];
        {
            const vfloat4* ap = reinterpret_cast<const vfloat4*>(Al + d * 8);
            vfloat4 a0 = ap[0], a1 = ap[1];
            An[0]=a0.x; An[1]=a0.y; An[2]=a0.z; An[3]=a0.w;
            An[4]=a1.x; An[5]=a1.y; An[6]=a1.z; An[7]=a1.w;
#pragma unroll
            for (int n = 0; n < 8; n++) An[n] = -__expf(An[n]);
        }
        const float Dd = Dp[d];
        const int lbase = c * 16;

        float Ap[8], Wp[8];
#pragma unroll
        for (int n = 0; n < 8; n++) { Ap[n] = 1.f; Wp[n] = 0.f; }
        for (int i = 0; i < 16; i++) {
            const int ll = lbase + i;
            const float dl = sdl[ll * 33 + d];
            const float ul = su[d * 132 + ll];
            const float du = dl * ul;
            const vfloat4* bp = reinterpret_cast<const vfloat4*>(sB + ll * 8);
            vfloat4 b0 = bp[0], b1 = bp[1];
            float Bv[8] = {b0.x,b0.y,b0.z,b0.w,b1.x,b1.y,b1.z,b1.w};
#pragma unroll
            for (int n = 0; n < 8; n++) {
                const float dA = __expf(dl * An[n]);
                Wp[n] = dA * Wp[n] + du * Bv[n];
                Ap[n] *= dA;
            }
        }
#pragma unroll
        for (int s = 1; s < 8; s <<= 1) {
#pragma unroll
            for (int n = 0; n < 8; n++) {
                const float Au = __shfl_up(Ap[n], s, 8);
                const float Wu = __shfl_up(Wp[n], s, 8);
                if (c >= s) {
                    Wp[n] = Ap[n] * Wu + Wp[n];
                    Ap[n] = Ap[n] * Au;
                }
            }
        }
        float hn[8];
#pragma unroll
        for (int n = 0; n < 8; n++) {
            const float Wu = __shfl_up(Wp[n], 1, 8);
            hn[n] = (c == 0) ? 0.f : Wu;
        }
        for (int i = 0; i < 16; i++) {
            const int ll = lbase + i;
            const float dl = sdl[ll * 33 + d];
            const float ul = su[d * 132 + ll];
            const float du = dl * ul;
            const vfloat4* bp = reinterpret_cast<const vfloat4*>(sB + ll * 8);
            const vfloat4* cp = reinterpret_cast<const vfloat4*>(sC + ll * 8);
            vfloat4 b0 = bp[0], b1 = bp[1];
            vfloat4 c0 = cp[0], c1 = cp[1];
            float Bv[8] = {b0.x,b0.y,b0.z,b0.w,b1.x,b1.y,b1.z,b1.w};
            float Cv[8] = {c0.x,c0.y,c0.z,c0.w,c1.x,c1.y,c1.z,c1.w};
            float y = 0.f;
#pragma unroll
            for (int n = 0; n < 8; n++) {
                const float dA = __expf(dl * An[n]);
                hn[n] = dA * hn[n] + du * Bv[n];
                y += hn[n] * Cv[n];
            }
            sy[d * 132 + ll] = y + Dd * ul;
        }
    }
    __syncthreads();

    // Phase 7: store y (fwd orientation, [b][d][l]) to global; 8 elems/thread
    for (int i = tid; i < 4096; i += 512) {
        const int d = i >> 7, li = i & 127;
        const int gl = dir ? (127 - li) : li;
        g_y[dir][(b * D_M + d) * L_SEQ + gl] = sy[d * 132 + li];
    }
    __syncthreads();

    // Arrival: second tail block of this batch runs the final stage
    if (tid == 0) {
        __threadfence();
        const int old = atomicAdd(&g_done[b], 1);
        const int win = (old == 1);
        if (win) {
            atomicExch(&g_done[b], 0);
            __threadfence();
        }
        s_flag = win;
    }
    __syncthreads();

    if (s_flag) {
        // ---- Final (winner): v build by all threads, then 128 threads LN + m-dot ----
        float* sv = S;            // [128][33]
        const float* y0 = g_y[0] + (size_t)b * D_M * L_SEQ;
        const float* y1 = g_y[1] + (size_t)b * D_M * L_SEQ;

#pragma unroll
        for (int k = 0; k < 8; k++) {
            const int d = qq * 8 + k;
            const float yc = y0[d * L_SEQ + l] + y1[d * L_SEQ + l];
            sv[l * 33 + d] = yc * zs[k];
        }
        __syncthreads();

        if (tid < 128) {
            float vv[D_M];
            float mean = 0.f;
#pragma unroll
            for (int d = 0; d < D_M; d++) { vv[d] = sv[l * 33 + d]; mean += vv[d]; }
            mean *= (1.f / D_M);
            float var = 0.f;
#pragma unroll
            for (int d = 0; d < D_M; d++) { float t = vv[d] - mean; var += t * t; }
            var *= (1.f / D_M);
            const float rs = rsqrtf(var + 1e-5f);

            float acc = b2[0];
#pragma unroll
            for (int d = 0; d < D_M; d++) {
                const float y = ((vv[d] - mean) * rs * ng[d] + nb[d]) * 0.5f;
                acc += y * smm[d];
            }
            out[b * L_SEQ + l] = 1.f / (1.f + __expf(-acc));
        }
        __syncthreads();
    }

    // Cleanup: reset g_cnt[b] after BOTH tail blocks are fully done
    if (tid == 0) {
        const int old = atomicAdd(&g_cnt[b], 1);
        if (old == 129) atomicExch(&g_cnt[b], 0);
    }
}

extern "C" void kernel_launch(void* const* d_in, const int* in_sizes, int n_in,
                              void* d_out, int out_size, void* d_ws, size_t ws_size,
                              hipStream_t stream) {
    const float* x        = (const float*)d_in[0];
    const float* w1       = (const float*)d_in[1];
    const float* b1       = (const float*)d_in[2];
    const float* ln_g     = (const float*)d_in[3];
    const float* ln_b     = (const float*)d_in[4];
    const float* in_proj  = (const float*)d_in[5];
    const float* cw_f     = (const float*)d_in[6];
    const float* cb_f     = (const float*)d_in[7];
    const float* xp_f     = (const float*)d_in[8];
    const float* dtw_f    = (const float*)d_in[9];
    const float* dtb_f    = (const float*)d_in[10];
    const float* Al_f     = (const float*)d_in[11];
    const float* Dp_f     = (const float*)d_in[12];
    const float* cw_b     = (const float*)d_in[13];
    const float* cb_b     = (const float*)d_in[14];
    const float* xp_b     = (const float*)d_in[15];
    const float* dtw_b    = (const float*)d_in[16];
    const float* dtb_b    = (const float*)d_in[17];
    const float* Al_b     = (const float*)d_in[18];
    const float* Dp_b     = (const float*)d_in[19];
    const float* norm_g   = (const float*)d_in[20];
    const float* norm_b   = (const float*)d_in[21];
    const float* Wout     = (const float*)d_in[22];
    const float* w2       = (const float*)d_in[23];
    const float* b2       = (const float*)d_in[24];

    fused<<<B_SZ * L_SEQ, 512, 0, stream>>>(
        x, w1, b1, ln_g, ln_b, in_proj,
        cw_f, cb_f, xp_f, dtw_f, dtb_f, Al_f, Dp_f,
        cw_b, cb_b, xp_b, dtw_b, dtb_b, Al_b, Dp_b,
        norm_g, norm_b, Wout, w2, b2, (float*)d_out);
}